// Round 9
// baseline (1625.359 us; speedup 1.0000x reference)
//
#include <hip/hip_runtime.h>
#include <stdint.h>

#define TSTEPS 50
#define BATCH  1024
#define INDIM  405
#define KP     448      // padded K for gx GEMM (7 x 64)
#define KH     224      // padded K for recurrent mats (7 x 32)
#define HBS    232      // shbf row stride in shorts
#define HDIM   200
#define G4H    800      // 4*H
#define NMEM   128
#define DMEM   40
#define DPAD   44       // sM row stride: 16B-aligned
#define RH     4
#define RD     160      // RH*DMEM
#define NWAY   5
#define GAMMA_ 0.99f
#define NG     4        // batches per block; 256 blocks x 512 thr, 1 block/CU
#define WROWS  928      // gx GEMM W rows padded

typedef __attribute__((ext_vector_type(8))) short short8;
typedef __attribute__((ext_vector_type(4))) float f32x4;

__device__ __forceinline__ float sigmoidf_(float x) {
    return 1.f / (1.f + __expf(-x));
}
__device__ __forceinline__ float ftanh(float x) {
    float e = __expf(2.f * x);
    return 1.f - 2.f / (e + 1.f);
}
__device__ __forceinline__ unsigned short f2bf(float f) {   // RNE f32->bf16
    uint32_t u = __float_as_uint(f);
    uint32_t r = u + 0x7FFFu + ((u >> 16) & 1u);
    return (unsigned short)(r >> 16);
}
__device__ __forceinline__ float bf2f(unsigned short h) {
    return __uint_as_float(((uint32_t)h) << 16);
}

// ---- recurrent weights -> bf16 row-major, zero-padded K (MFMA A-frag) -----
__global__ __launch_bounds__(256) void convert_rec(const float* __restrict__ W_hh,
                                                   const float* __restrict__ Wk,
                                                   unsigned short* __restrict__ Whh_bf,
                                                   unsigned short* __restrict__ Wk_bf) {
    int i = blockIdx.x * 256 + threadIdx.x;
    const int whh_e = G4H * KH;
    const int wk_e  = RD * KH;
    if (i < whh_e) {
        int o = i / KH, k = i % KH;
        Whh_bf[i] = f2bf(k < HDIM ? W_hh[o * HDIM + k] : 0.f);
    } else if (i < whh_e + wk_e) {
        int e = i - whh_e;
        int o = e / KH, k = e % KH;
        Wk_bf[e] = f2bf(k < HDIM ? Wk[o * HDIM + k] : 0.f);
    }
}

// ---------------- split f32 -> (hi, lo) bf16, zero-padded K (gx GEMM) ------
__global__ __launch_bounds__(256) void convert_A(const float* __restrict__ x,
                                                 unsigned short* __restrict__ Ahi,
                                                 unsigned short* __restrict__ Alo) {
    int c = blockIdx.x * 256 + threadIdx.x;
    int r = blockIdx.y;
    if (c >= KP) return;
    float v = (c < INDIM) ? x[(size_t)r * INDIM + c] : 0.f;
    unsigned short hi = f2bf(v);
    unsigned short lo = f2bf(v - bf2f(hi));
    size_t o = (size_t)r * KP + c;
    Ahi[o] = hi;
    Alo[o] = lo;
}

__global__ __launch_bounds__(256) void convert_W(const float* __restrict__ W_ih,
                                                 unsigned short* __restrict__ Wpk) {
    int c = blockIdx.x * 256 + threadIdx.x;
    int n = blockIdx.y;
    int sec = blockIdx.z;
    if (c >= KP) return;
    float v = (n < G4H && c < INDIM) ? W_ih[(size_t)n * INDIM + c] : 0.f;
    unsigned short hi = f2bf(v);
    size_t o = (size_t)sec * WROWS * KP + (size_t)n * KP + c;
    Wpk[o] = (sec == 0) ? hi : f2bf(v - bf2f(hi));
}

// ---------------- gx GEMM via 3-term split-bf16 MFMA ----------------------
__global__ __launch_bounds__(256) void gx_gemm_mfma(
        const unsigned short* __restrict__ Ahi,
        const unsigned short* __restrict__ Alo,
        const unsigned short* __restrict__ Wpk,
        const float* __restrict__ b_ih, const float* __restrict__ b_hh,
        float* __restrict__ gx) {
    __shared__ unsigned short Alds[128 * 64];
    __shared__ unsigned short Blds[128 * 64];
    const int tid = threadIdx.x;
    const int wv = tid >> 6, ln = tid & 63;
    const int wr = wv >> 1, wc = wv & 1;
    const int n0 = blockIdx.x * 128;
    const int m0 = blockIdx.y * 128;

    f32x4 acc[4][4];
#pragma unroll
    for (int m = 0; m < 4; ++m)
#pragma unroll
        for (int n = 0; n < 4; ++n) acc[m][n] = (f32x4){0.f, 0.f, 0.f, 0.f};

    int erow[4], ecol[4];
#pragma unroll
    for (int i = 0; i < 4; ++i) {
        int e = (i * 4 + wv) * 512 + ln * 8;
        erow[i] = e >> 6;
        ecol[i] = e & 63;
    }

    const unsigned short* Whi = Wpk;
    const unsigned short* Wlo = Wpk + (size_t)WROWS * KP;

#pragma unroll 1
    for (int s = 0; s < 3; ++s) {
        const unsigned short* Ab = ((s == 2) ? Alo : Ahi) + (size_t)m0 * KP;
        const unsigned short* Bb = ((s == 1) ? Wlo : Whi) + (size_t)n0 * KP;

        short8 ar[4], br[4];
#pragma unroll
        for (int i = 0; i < 4; ++i) {
            ar[i] = *(const short8*)&Ab[(size_t)erow[i] * KP + ecol[i]];
            br[i] = *(const short8*)&Bb[(size_t)erow[i] * KP + ecol[i]];
        }

#pragma unroll 1
        for (int k0 = 0; k0 < KP; k0 += 64) {
            __syncthreads();
#pragma unroll
            for (int i = 0; i < 4; ++i) {
                int e = (i * 4 + wv) * 512 + ln * 8;
                *(short8*)&Alds[e] = ar[i];
                *(short8*)&Blds[e] = br[i];
            }
            __syncthreads();
            if (k0 + 64 < KP) {
#pragma unroll
                for (int i = 0; i < 4; ++i) {
                    ar[i] = *(const short8*)&Ab[(size_t)erow[i] * KP + k0 + 64 + ecol[i]];
                    br[i] = *(const short8*)&Bb[(size_t)erow[i] * KP + k0 + 64 + ecol[i]];
                }
            }
#pragma unroll
            for (int ks = 0; ks < 2; ++ks) {
                short8 af[4], bf[4];
                int kcol = ks * 32 + (ln >> 4) * 8;
#pragma unroll
                for (int m = 0; m < 4; ++m) {
                    int row = wr * 64 + m * 16 + (ln & 15);
                    af[m] = *(const short8*)&Alds[row * 64 + kcol];
                }
#pragma unroll
                for (int n = 0; n < 4; ++n) {
                    int row = wc * 64 + n * 16 + (ln & 15);
                    bf[n] = *(const short8*)&Blds[row * 64 + kcol];
                }
#pragma unroll
                for (int m = 0; m < 4; ++m)
#pragma unroll
                    for (int n = 0; n < 4; ++n)
                        acc[m][n] = __builtin_amdgcn_mfma_f32_16x16x32_bf16(
                            af[m], bf[n], acc[m][n], 0, 0, 0);
            }
        }
    }

#pragma unroll
    for (int n = 0; n < 4; ++n) {
        int col = n0 + wc * 64 + n * 16 + (ln & 15);
        if (col >= G4H) continue;
        float bias = b_ih[col] + b_hh[col];
#pragma unroll
        for (int m = 0; m < 4; ++m) {
#pragma unroll
            for (int j = 0; j < 4; ++j) {
                int row = m0 + wr * 64 + m * 16 + (ln >> 4) * 4 + j;
                gx[(size_t)row * G4H + col] = acc[m][n][j] + bias;
            }
        }
    }
}

// ---------------- f32 fallback GEMM ---------------------------------------
__global__ __launch_bounds__(256) void gx_gemm(const float* __restrict__ x,
                                               const float* __restrict__ W_ih,
                                               const float* __restrict__ b_ih,
                                               const float* __restrict__ b_hh,
                                               float* __restrict__ gx) {
    const int BM = 128, BN = 80, BK = 16;
    __shared__ float As[BK][BM];
    __shared__ float Bs[BK][BN];
    int m0 = blockIdx.y * BM;
    int n0 = blockIdx.x * BN;
    int tid = threadIdx.x;
    int tm = tid >> 4, tn = tid & 15;
    float acc[8][5];
#pragma unroll
    for (int i = 0; i < 8; ++i)
#pragma unroll
        for (int j = 0; j < 5; ++j) acc[i][j] = 0.f;

    for (int k0 = 0; k0 < INDIM; k0 += BK) {
        {
            int row = tid >> 1, kk = (tid & 1) * 8;
            const float* ap = x + (size_t)(m0 + row) * INDIM + k0 + kk;
#pragma unroll
            for (int i = 0; i < 8; ++i)
                As[kk + i][row] = (k0 + kk + i < INDIM) ? ap[i] : 0.f;
        }
        if (tid < 160) {
            int col = tid >> 1, kk = (tid & 1) * 8;
            const float* bp = W_ih + (size_t)(n0 + col) * INDIM + k0 + kk;
#pragma unroll
            for (int i = 0; i < 8; ++i)
                Bs[kk + i][col] = (k0 + kk + i < INDIM) ? bp[i] : 0.f;
        }
        __syncthreads();
#pragma unroll
        for (int k = 0; k < BK; ++k) {
            float a[8], b[5];
#pragma unroll
            for (int i = 0; i < 8; ++i) a[i] = As[k][tm * 8 + i];
#pragma unroll
            for (int j = 0; j < 5; ++j) b[j] = Bs[k][tn * 5 + j];
#pragma unroll
            for (int i = 0; i < 8; ++i)
#pragma unroll
                for (int j = 0; j < 5; ++j) acc[i][j] += a[i] * b[j];
        }
        __syncthreads();
    }
#pragma unroll
    for (int j = 0; j < 5; ++j) {
        int n = n0 + tn * 5 + j;
        float bias = b_ih[n] + b_hh[n];
#pragma unroll
        for (int i = 0; i < 8; ++i) {
            int m = m0 + tm * 8 + i;
            gx[(size_t)m * G4H + n] = acc[i][j] + bias;
        }
    }
}

// ---------------- persistent NTM scan: NG=4, 512 thr, MFMA gates/keys ------
__global__ __launch_bounds__(512, 2) void ntm_scan(
        const float* __restrict__ gx,              // [T][B][800]
        const unsigned short* __restrict__ Whh_bf, // [800][224] bf16
        const unsigned short* __restrict__ Wk_bf,  // [160][224] bf16
        const float* __restrict__ bk,
        const float* __restrict__ Wsm,             // [4][200]
        const float* __restrict__ bs,
        const float* __restrict__ Wo,              // [5][360]
        const float* __restrict__ bo,
        float* __restrict__ out) {                 // [T][B][5]
    __shared__ float sM[NG][NMEM][DPAD];           // 90.1 KB
    __shared__ float sh[NG][HDIM];
    __shared__ unsigned short shbf_hi[16][HBS];
    __shared__ unsigned short shbf_lo[16][HBS];
    __shared__ float sgate[NG][G4H];
    __shared__ float swr[NG][RH][NMEM];
    __shared__ float sww[NG][RH][NMEM];
    __shared__ float sKs[NG][RH][NMEM];
    __shared__ float swu[NG][NMEM];
    __shared__ float swlu[NG][NMEM];
    __shared__ float sk[NG][RH][DMEM];
    __shared__ float sr[NG][RD];
    __shared__ float snk[NG][RH];
    __shared__ float ssig[NG][RH];
    __shared__ float snM[NG][NMEM];
    __shared__ float stmp[NG][NWAY];
    __shared__ int   sidx[NG];

    const int tid = threadIdx.x;
    const int b0  = blockIdx.x * NG;
    const int w   = tid >> 6, l = tid & 63;
    const int lr  = l & 15, lc = l >> 4;

    // ---- init ----
    for (int e = tid; e < NG * NMEM * DPAD; e += 512) ((float*)sM)[e] = 0.f;
    for (int e = tid; e < NG * HDIM; e += 512) ((float*)sh)[e] = 0.f;
    for (int e = tid; e < 16 * HBS; e += 512) { ((unsigned short*)shbf_hi)[e] = 0; ((unsigned short*)shbf_lo)[e] = 0; }
    for (int e = tid; e < NG * RH * NMEM; e += 512) ((float*)swr)[e] = 0.f;
    for (int e = tid; e < NG * NMEM; e += 512) { ((float*)swu)[e] = 0.f; ((float*)swlu)[e] = 1.f; }

    // B-phase state: pair0 = tid (always), pair1 = tid+512 (tid<288)
    const int p0g = tid / HDIM, p0j = tid - (tid / HDIM) * HDIM;
    const int p1  = tid + 512;
    const int p1g = p1 / HDIM, p1j = p1 - (p1 / HDIM) * HDIM;
    const bool hasP1 = (tid < G4H - 512);
    float c0 = 0.f, c1 = 0.f;
    float g0a, g0b, g0c, g0d, g1a = 0.f, g1b = 0.f, g1c = 0.f, g1d = 0.f;
    {
        const float* gp = gx + (size_t)(b0 + p0g) * G4H + p0j;
        g0a = gp[0]; g0b = gp[HDIM]; g0c = gp[2 * HDIM]; g0d = gp[3 * HDIM];
        if (hasP1) {
            const float* gq = gx + (size_t)(b0 + p1g) * G4H + p1j;
            g1a = gq[0]; g1b = gq[HDIM]; g1c = gq[2 * HDIM]; g1d = gq[3 * HDIM];
        }
    }
    __syncthreads();

    for (int t = 0; t < TSTEPS; ++t) {
        // ---- A: gates MFMA (tiles w+8i) | argmin wu on waves 6,7 ----
        {
            short8 bh[7], bl[7];
#pragma unroll
            for (int kk = 0; kk < 7; ++kk) {
                bh[kk] = *(const short8*)&shbf_hi[lr][kk * 32 + lc * 8];
                bl[kk] = *(const short8*)&shbf_lo[lr][kk * 32 + lc * 8];
            }
#pragma unroll
            for (int i = 0; i < 7; ++i) {
                int tile = w + 8 * i;
                if (tile < 50) {
                    f32x4 acc = (f32x4){0.f, 0.f, 0.f, 0.f};
                    const unsigned short* ap = Whh_bf + (size_t)(tile * 16 + lr) * KH + lc * 8;
#pragma unroll
                    for (int kk = 0; kk < 7; ++kk) {
                        short8 af = *(const short8*)&ap[kk * 32];
                        acc = __builtin_amdgcn_mfma_f32_16x16x32_bf16(af, bh[kk], acc, 0, 0, 0);
                        acc = __builtin_amdgcn_mfma_f32_16x16x32_bf16(af, bl[kk], acc, 0, 0, 0);
                    }
                    if (lr < NG) {
#pragma unroll
                        for (int j = 0; j < 4; ++j)
                            sgate[lr][tile * 16 + lc * 4 + j] = acc[j];
                    }
                }
            }
            if (w >= 6) {
#pragma unroll
                for (int rep = 0; rep < 2; ++rep) {
                    int g = (w - 6) * 2 + rep;
                    float v0 = swu[g][l], v1 = swu[g][l + 64];
                    bool p1_ = (v1 < v0);
                    float mv = p1_ ? v1 : v0;
                    int   mi = p1_ ? l + 64 : l;
#pragma unroll
                    for (int off = 32; off; off >>= 1) {
                        float ov = __shfl_xor(mv, off);
                        int   oi = __shfl_xor(mi, off);
                        if (ov < mv || (ov == mv && oi < mi)) { mv = ov; mi = oi; }
                    }
                    if (l == 0) sidx[g] = mi;
                }
            }
        }
        __syncthreads();

        // ---- B: LSTM cell (2 units/thread); h->bf16 split; gx prefetch ----
        {
            float ig = sigmoidf_(sgate[p0g][p0j] + g0a);
            float fg = sigmoidf_(sgate[p0g][p0j + HDIM] + g0b);
            float gv = ftanh(sgate[p0g][p0j + 2 * HDIM] + g0c);
            float og = sigmoidf_(sgate[p0g][p0j + 3 * HDIM] + g0d);
            c0 = fg * c0 + ig * gv;
            float h = og * ftanh(c0);
            sh[p0g][p0j] = h;
            unsigned short hi = f2bf(h);
            shbf_hi[p0g][p0j] = hi;
            shbf_lo[p0g][p0j] = f2bf(h - bf2f(hi));
            if (t + 1 < TSTEPS) {
                const float* gp = gx + ((size_t)(t + 1) * BATCH + b0 + p0g) * G4H + p0j;
                g0a = gp[0]; g0b = gp[HDIM]; g0c = gp[2 * HDIM]; g0d = gp[3 * HDIM];
            }
        }
        if (hasP1) {
            float ig = sigmoidf_(sgate[p1g][p1j] + g1a);
            float fg = sigmoidf_(sgate[p1g][p1j + HDIM] + g1b);
            float gv = ftanh(sgate[p1g][p1j + 2 * HDIM] + g1c);
            float og = sigmoidf_(sgate[p1g][p1j + 3 * HDIM] + g1d);
            c1 = fg * c1 + ig * gv;
            float h = og * ftanh(c1);
            sh[p1g][p1j] = h;
            unsigned short hi = f2bf(h);
            shbf_hi[p1g][p1j] = hi;
            shbf_lo[p1g][p1j] = f2bf(h - bf2f(hi));
            if (t + 1 < TSTEPS) {
                const float* gq = gx + ((size_t)(t + 1) * BATCH + b0 + p1g) * G4H + p1j;
                g1a = gq[0]; g1b = gq[HDIM]; g1c = gq[2 * HDIM]; g1d = gq[3 * HDIM];
            }
        }
        __syncthreads();

        // ---- C: keys MFMA (tiles w, w+8) | sigma on waves 2-5 ----
        {
            short8 bh[7], bl[7];
#pragma unroll
            for (int kk = 0; kk < 7; ++kk) {
                bh[kk] = *(const short8*)&shbf_hi[lr][kk * 32 + lc * 8];
                bl[kk] = *(const short8*)&shbf_lo[lr][kk * 32 + lc * 8];
            }
#pragma unroll
            for (int i = 0; i < 2; ++i) {
                int tile = w + 8 * i;
                if (tile < 10) {
                    f32x4 acc = (f32x4){0.f, 0.f, 0.f, 0.f};
                    const unsigned short* ap = Wk_bf + (size_t)(tile * 16 + lr) * KH + lc * 8;
#pragma unroll
                    for (int kk = 0; kk < 7; ++kk) {
                        short8 af = *(const short8*)&ap[kk * 32];
                        acc = __builtin_amdgcn_mfma_f32_16x16x32_bf16(af, bh[kk], acc, 0, 0, 0);
                        acc = __builtin_amdgcn_mfma_f32_16x16x32_bf16(af, bl[kk], acc, 0, 0, 0);
                    }
                    if (lr < NG) {
#pragma unroll
                        for (int j = 0; j < 4; ++j) {
                            int o = tile * 16 + lc * 4 + j;
                            sk[lr][o / DMEM][o % DMEM] = ftanh(acc[j] + bk[o]);
                        }
                    }
                }
            }
            if (w >= 2 && w < 6) {
                int g = w - 2;
#pragma unroll
                for (int r = 0; r < RH; ++r) {
                    float a = 0.f;
                    for (int j = l; j < HDIM; j += 64) a += sh[g][j] * Wsm[r * HDIM + j];
#pragma unroll
                    for (int off = 32; off; off >>= 1) a += __shfl_xor(a, off);
                    if (l == 0) ssig[g][r] = sigmoidf_(ftanh(a + bs[r]));
                }
            }
        }
        __syncthreads();

        // ---- E2': ww + zero-LU-row + rank-4 M update; one thread per (g,m) ----
        {
            int g = tid >> 7, m = tid & 127;
            float sg0 = ssig[g][0], sg1 = ssig[g][1], sg2 = ssig[g][2], sg3 = ssig[g][3];
            float wl = swlu[g][m];
            float w0 = sg0 * swr[g][0][m] + (1.f - sg0) * wl;
            float w1 = sg1 * swr[g][1][m] + (1.f - sg1) * wl;
            float w2 = sg2 * swr[g][2][m] + (1.f - sg2) * wl;
            float w3 = sg3 * swr[g][3][m] + (1.f - sg3) * wl;
            sww[g][0][m] = w0; sww[g][1][m] = w1;
            sww[g][2][m] = w2; sww[g][3][m] = w3;
            bool zr = (m == sidx[g]);
#pragma unroll
            for (int q = 0; q < 10; ++q) {
                int d = q * 4;
                float4 mv = *(const float4*)&sM[g][m][d];
                float4 k0 = *(const float4*)&sk[g][0][d];
                float4 k1 = *(const float4*)&sk[g][1][d];
                float4 k2 = *(const float4*)&sk[g][2][d];
                float4 k3 = *(const float4*)&sk[g][3][d];
                float4 o;
                o.x = (zr ? 0.f : mv.x) + w0 * k0.x + w1 * k1.x + w2 * k2.x + w3 * k3.x;
                o.y = (zr ? 0.f : mv.y) + w0 * k0.y + w1 * k1.y + w2 * k2.y + w3 * k3.y;
                o.z = (zr ? 0.f : mv.z) + w0 * k0.z + w1 * k1.z + w2 * k2.z + w3 * k3.z;
                o.w = (zr ? 0.f : mv.w) + w0 * k0.w + w1 * k1.w + w2 * k2.w + w3 * k3.w;
                *(float4*)&sM[g][m][d] = o;
            }
            if (tid < 16) {
                int g2 = tid >> 2, r2 = tid & 3;
                float a0 = 0.f, a1 = 0.f, a2 = 0.f, a3 = 0.f;
#pragma unroll
                for (int q = 0; q < 10; ++q) {
                    float4 kv = *(const float4*)&sk[g2][r2][q * 4];
                    a0 += kv.x * kv.x; a1 += kv.y * kv.y;
                    a2 += kv.z * kv.z; a3 += kv.w * kv.w;
                }
                snk[g2][r2] = sqrtf((a0 + a1) + (a2 + a3));
            }
        }
        __syncthreads();

        // ---- NF: per (g,m): read sM row once -> 4 cosine dots + norm ----
        {
            int g = tid >> 7, m = tid & 127;
            float d0 = 0.f, d1 = 0.f, d2 = 0.f, d3 = 0.f, nn = 0.f;
#pragma unroll
            for (int q = 0; q < 10; ++q) {
                int d = q * 4;
                float4 mv = *(const float4*)&sM[g][m][d];
                float4 k0 = *(const float4*)&sk[g][0][d];
                float4 k1 = *(const float4*)&sk[g][1][d];
                float4 k2 = *(const float4*)&sk[g][2][d];
                float4 k3 = *(const float4*)&sk[g][3][d];
                d0 += k0.x * mv.x + k0.y * mv.y + k0.z * mv.z + k0.w * mv.w;
                d1 += k1.x * mv.x + k1.y * mv.y + k1.z * mv.z + k1.w * mv.w;
                d2 += k2.x * mv.x + k2.y * mv.y + k2.z * mv.z + k2.w * mv.w;
                d3 += k3.x * mv.x + k3.y * mv.y + k3.z * mv.z + k3.w * mv.w;
                nn += mv.x * mv.x + mv.y * mv.y + mv.z * mv.z + mv.w * mv.w;
            }
            sKs[g][0][m] = d0; sKs[g][1][m] = d1;
            sKs[g][2][m] = d2; sKs[g][3][m] = d3;
            snM[g][m] = sqrtf(nn);
        }
        __syncthreads();

        // ---- G: cosine normalize + softmax over m; 16 (g,r) on 8 waves x2 ----
#pragma unroll
        for (int rep = 0; rep < 2; ++rep) {
            int idx = w + rep * 8;
            int g = idx >> 2, r = idx & 3;
            float ink = snk[g][r];
            float a = sKs[g][r][l] / (ink * snM[g][l]);
            float b = sKs[g][r][l + 64] / (ink * snM[g][l + 64]);
            float mx = fmaxf(a, b);
#pragma unroll
            for (int off = 32; off; off >>= 1) mx = fmaxf(mx, __shfl_xor(mx, off));
            float ea = __expf(a - mx), eb = __expf(b - mx);
            float s = ea + eb;
#pragma unroll
            for (int off = 32; off; off >>= 1) s += __shfl_xor(s, off);
            float inv = 1.f / s;
            swr[g][r][l]      = ea * inv;
            swr[g][r][l + 64] = eb * inv;
        }
        __syncthreads();

        // ---- H: read vectors (160 thr) | usage update (rest, 512 items) ----
        if (tid < 160) {
            int g = tid / 40, rd4 = tid % 40, r = rd4 / 10, d4 = rd4 % 10;
            float a0 = 0.f, a1 = 0.f, a2 = 0.f, a3 = 0.f;
            for (int m = 0; m < NMEM; ++m) {
                float wv = swr[g][r][m];
                float4 mv = *(const float4*)&sM[g][m][d4 * 4];
                a0 += wv * mv.x; a1 += wv * mv.y;
                a2 += wv * mv.z; a3 += wv * mv.w;
            }
            float4 res = {a0, a1, a2, a3};
            *(float4*)&sr[g][r * DMEM + d4 * 4] = res;
        } else {
            for (int e = tid - 160; e < 512; e += 352) {
                int g = e >> 7, m = e & 127;
                float wu = GAMMA_ * swu[g][m];
#pragma unroll
                for (int r = 0; r < RH; ++r) wu += swr[g][r][m] + sww[g][r][m];
                swu[g][m] = wu;
            }
        }
        __syncthreads();

        // ---- I1: head GEMV waves 0-4 (16-lane groups) | kth waves 5,6 ----
        if (tid < 320) {
            int q = tid >> 4, ln = tid & 15;
            int g = q / NWAY, o = q - (q / NWAY) * NWAY;
            const float* wrow = Wo + o * (HDIM + RD);
            float acc = 0.f;
            for (int j = ln; j < HDIM; j += 16) acc += sh[g][j] * wrow[j];
            for (int d = ln; d < RD; d += 16) acc += sr[g][d] * wrow[HDIM + d];
            acc += __shfl_xor(acc, 8, 16);
            acc += __shfl_xor(acc, 4, 16);
            acc += __shfl_xor(acc, 2, 16);
            acc += __shfl_xor(acc, 1, 16);
            if (ln == 0) stmp[g][o] = acc + bo[o];
        } else if (w == 5 || w == 6) {
#pragma unroll
            for (int rep = 0; rep < 2; ++rep) {
                int g = (w - 5) * 2 + rep;
                float o0 = swu[g][l], o1 = swu[g][l + 64];
                float v0 = o0, v1 = o1, kth = 0.f;
#pragma unroll
                for (int it = 0; it < RH; ++it) {
                    bool p1_ = (v1 < v0);
                    float mv = p1_ ? v1 : v0;
                    int   mi = p1_ ? l + 64 : l;
                    for (int off = 32; off; off >>= 1) {
                        float ov = __shfl_xor(mv, off);
                        int   oi = __shfl_xor(mi, off);
                        if (ov < mv || (ov == mv && oi < mi)) { mv = ov; mi = oi; }
                    }
                    kth = mv;
                    if (mi == l) v0 = __builtin_inff();
                    else if (mi == l + 64) v1 = __builtin_inff();
                }
                swlu[g][l]      = (o0 <= kth) ? 1.f : 0.f;
                swlu[g][l + 64] = (o1 <= kth) ? 1.f : 0.f;
            }
        }
        __syncthreads();

        // ---- I2: final sigmoid+softmax + store (no trailing barrier) ----
        if (tid < NG) {
            int g = tid;
            float v[NWAY], mx = -1e30f;
#pragma unroll
            for (int o = 0; o < NWAY; ++o) { v[o] = sigmoidf_(stmp[g][o]); mx = fmaxf(mx, v[o]); }
            float s = 0.f;
#pragma unroll
            for (int o = 0; o < NWAY; ++o) { v[o] = __expf(v[o] - mx); s += v[o]; }
            float inv = 1.f / s;
            float* op = out + ((size_t)t * BATCH + (b0 + g)) * NWAY;
#pragma unroll
            for (int o = 0; o < NWAY; ++o) op[o] = v[o] * inv;
        }
    }
}

extern "C" void kernel_launch(void* const* d_in, const int* in_sizes, int n_in,
                              void* d_out, int out_size, void* d_ws, size_t ws_size,
                              hipStream_t stream) {
    const float* x    = (const float*)d_in[0];
    const float* W_ih = (const float*)d_in[1];
    const float* W_hh = (const float*)d_in[2];
    const float* b_ih = (const float*)d_in[3];
    const float* b_hh = (const float*)d_in[4];
    const float* Wk   = (const float*)d_in[5];
    const float* bk   = (const float*)d_in[6];
    const float* Wsm  = (const float*)d_in[7];
    const float* bs   = (const float*)d_in[8];
    const float* Wo   = (const float*)d_in[9];
    const float* bo   = (const float*)d_in[10];
    float* out = (float*)d_out;

    const size_t gx_elems  = (size_t)TSTEPS * BATCH * G4H;  // 40,960,000 f32
    const size_t whh_e     = (size_t)G4H * KH;              // u16
    const size_t wk_e      = (size_t)RD * KH;               // u16
    const size_t a_elems   = (size_t)TSTEPS * BATCH * KP;   // u16 each
    const size_t w_elems   = (size_t)2 * WROWS * KP;        // u16
    const size_t need_base = gx_elems * 4 + (whh_e + wk_e) * 2;
    const size_t need_mfma = need_base + (2 * a_elems + w_elems) * 2;
    if (ws_size < need_base) return;

    float* gxb = (float*)d_ws;
    unsigned short* Whh_bf = (unsigned short*)(gxb + gx_elems);
    unsigned short* Wk_bf  = Whh_bf + whh_e;

    {
        int tot = (int)(whh_e + wk_e);
        convert_rec<<<dim3((tot + 255) / 256), dim3(256), 0, stream>>>(W_hh, Wk, Whh_bf, Wk_bf);
    }

    if (ws_size >= need_mfma) {
        unsigned short* Ahi = Wk_bf + wk_e;
        unsigned short* Alo = Ahi + a_elems;
        unsigned short* Wpk = Alo + a_elems;
        convert_A<<<dim3(2, TSTEPS * BATCH), dim3(256), 0, stream>>>(x, Ahi, Alo);
        convert_W<<<dim3(2, WROWS, 2), dim3(256), 0, stream>>>(W_ih, Wpk);
        gx_gemm_mfma<<<dim3(7, (TSTEPS * BATCH) / 128), dim3(256), 0, stream>>>(
            Ahi, Alo, Wpk, b_ih, b_hh, gxb);
    } else {
        gx_gemm<<<dim3(G4H / 80, (TSTEPS * BATCH) / 128), dim3(256), 0, stream>>>(
            x, W_ih, b_ih, b_hh, gxb);
    }

    ntm_scan<<<dim3(BATCH / NG), dim3(512), 0, stream>>>(
        gxb, Whh_bf, Wk_bf, bk, Wsm, bs, Wo, bo, out);
}